// Round 8
// baseline (763.272 us; speedup 1.0000x reference)
//
#include <hip/hip_runtime.h>
#include <hip/hip_bf16.h>
#include <math.h>

#define NN 50000
#define FIN 128
#define CC 64
#define HH 4
#define HC 256
#define EE 500000
#define GG 32
#define LL 4

typedef __hip_bfloat16 bf16;

__device__ __forceinline__ float b2f(bf16 v){ return __bfloat162float(v); }
__device__ __forceinline__ bf16 f2b(float v){ return __float2bfloat16(v); }
__device__ __forceinline__ void unpack2(unsigned u, float& a, float& b){
  union { unsigned q; float f; } x, y;
  x.q = u << 16; y.q = u & 0xffff0000u; a = x.f; b = y.f;
}
__device__ __forceinline__ float clamp4(float v){ return fminf(fmaxf(v, -1e4f), 1e4f); }
__device__ __forceinline__ unsigned pack2bf(float a, float b){
  bf16 x = f2b(clamp4(a)), y = f2b(clamp4(b));
  unsigned short ux = *(unsigned short*)&x, uy = *(unsigned short*)&y;
  return (unsigned)ux | ((unsigned)uy << 16);
}
__device__ __forceinline__ float selu_f(float y){
  const float SS = 1.0507009873554805f, SA = 1.6732632423543772f;
  return y > 0.f ? SS*y : SS*SA*(__expf(y) - 1.f);
}
// flag-aware integer load: w8!=0 -> int64, else int32
__device__ __forceinline__ int ld_i(const void* p, int i, int w8){
  if (w8) return (int)((const long long*)p)[i];
  return ((const int*)p)[i];
}

// flags[0]: edge_index is int64; flags[1]: batch is int64; flags[2]: floats are fp32
__global__ void k_detect(const void* ei, const void* batch, const void* lnw, int* flags){
  int lane = threadIdx.x;           // 64 threads
  const int* w  = (const int*)ei;
  const int* wb = (const int*)batch;
  int bad_e = (lane < 32) ? (w[2*(lane*15625) + 1] != 0) : 0;
  int bad_b = (lane < 32) ? (wb[25001 + 2*lane] != 0) : 0;
  unsigned long long me = __ballot(bad_e);
  unsigned long long mb = __ballot(bad_b);
  if (lane == 0){
    flags[0] = (me == 0ULL) ? 1 : 0;
    flags[1] = (mb == 0ULL) ? 1 : 0;
    const unsigned short* lw = (const unsigned short*)lnw;
    flags[2] = (lw[0] == 0x0000 && lw[1] == 0x3F80) ? 1 : 0;
  }
}

__global__ __launch_bounds__(256) void k_zero(int* p, int n){
  int i = blockIdx.x*256 + threadIdx.x;
  if (i < n) p[i] = 0;
}

// ---- convert all small weights to canonical fp32 (143169 elements total) ----
__global__ __launch_bounds__(256) void k_cvt(
    const void* Wp, const void* Wl, const void* bl, const void* Wr, const void* br,
    const void* att, const void* cb, const void* lnw, const void* lnb,
    const void* Wh, const void* bh, float* dst, const int* flags){
  int i = blockIdx.x*256 + threadIdx.x;
  if (i >= 143169) return;
  const void* src; int idx;
  if      (i < 8192)   { src = Wp;  idx = i; }
  else if (i < 73728)  { src = Wl;  idx = i - 8192; }
  else if (i < 74752)  { src = bl;  idx = i - 73728; }
  else if (i < 140288) { src = Wr;  idx = i - 74752; }
  else if (i < 141312) { src = br;  idx = i - 140288; }
  else if (i < 142336) { src = att; idx = i - 141312; }
  else if (i < 142592) { src = cb;  idx = i - 142336; }
  else if (i < 142848) { src = lnw; idx = i - 142592; }
  else if (i < 143104) { src = lnb; idx = i - 142848; }
  else if (i < 143168) { src = Wh;  idx = i - 143104; }
  else                 { src = bh;  idx = 0; }
  float v = flags[2] ? ((const float*)src)[idx] : b2f(((const bf16*)src)[idx]);
  dst[i] = v;
}

// ---------------- edge histogram by dst ----------------
__global__ __launch_bounds__(256) void k_hist(const void* __restrict__ ei, int* __restrict__ deg,
                                              const int* __restrict__ flags){
  int e = blockIdx.x*256 + threadIdx.x;
  if (e < EE){
    int d = ld_i(ei, EE + e, flags[0]);
    if ((unsigned)d < NN) atomicAdd(&deg[d], 1);
  }
}

// ---------------- parallel 3-stage exclusive scan over deg[NN] ----------------
__global__ __launch_bounds__(256) void k_scan1(const int* __restrict__ deg, int* __restrict__ off,
                                               int* __restrict__ btot){
  int t = threadIdx.x;
  int i = blockIdx.x*256 + t;
  int v = (i < NN) ? deg[i] : 0;
  int incl = v;
  #pragma unroll
  for (int dl = 1; dl < 64; dl <<= 1){
    int u = __shfl_up(incl, dl, 64);
    if ((t & 63) >= dl) incl += u;
  }
  __shared__ int wt[4];
  if ((t & 63) == 63) wt[t >> 6] = incl;
  __syncthreads();
  int base = 0;
  for (int ww = 0; ww < (t >> 6); ++ww) base += wt[ww];
  incl += base;
  if (i < NN) off[i + 1] = incl;
  if (t == 255) btot[blockIdx.x] = incl;
}

__global__ __launch_bounds__(256) void k_scan2(const int* __restrict__ btot, int* __restrict__ boff, int nb){
  int t = threadIdx.x;
  int v = (t < nb) ? btot[t] : 0;
  int incl = v;
  #pragma unroll
  for (int dl = 1; dl < 64; dl <<= 1){
    int u = __shfl_up(incl, dl, 64);
    if ((t & 63) >= dl) incl += u;
  }
  __shared__ int wt[4];
  if ((t & 63) == 63) wt[t >> 6] = incl;
  __syncthreads();
  int base = 0;
  for (int ww = 0; ww < (t >> 6); ++ww) base += wt[ww];
  incl += base;
  if (t < 256) boff[t] = incl - v;   // exclusive
}

__global__ __launch_bounds__(256) void k_scan3(int* __restrict__ off, int* __restrict__ cursor,
                                               const int* __restrict__ deg, const int* __restrict__ boff){
  int i = blockIdx.x*256 + threadIdx.x;
  if (i >= NN) return;
  int v = off[i + 1] + boff[i >> 8];
  off[i + 1] = v;
  cursor[i] = v - deg[i];
  if (i == 0) off[0] = 0;
}

// ssrc stores BYTE offsets of the src row (s * 512)
__global__ __launch_bounds__(256) void k_scatter(const void* __restrict__ ei, int* __restrict__ cursor,
                                                 int* __restrict__ ssrc, const int* __restrict__ flags){
  int e = blockIdx.x*256 + threadIdx.x;
  if (e < EE){
    int f = flags[0];
    int s = ld_i(ei, e, f);
    int d = ld_i(ei, EE + e, f);
    if ((unsigned)d < NN && (unsigned)s < NN){
      int p = atomicAdd(&cursor[d], 1);
      ssrc[p] = s << 9;
    }
  }
}

// ---------------- graph boundaries (batch sorted) ----------------
__global__ __launch_bounds__(256) void k_gbounds(const void* __restrict__ batch, int* __restrict__ gstart,
                                                 const int* __restrict__ flags){
  int i = blockIdx.x*256 + threadIdx.x;
  if (i >= NN) return;
  int f = flags[1];
  int b = ld_i(batch, i, f);
  b = min(max(b, 0), GG - 1);
  if (i == 0){ for (int q = 0; q <= b; ++q) gstart[q] = 0; }
  else {
    int pb = ld_i(batch, i - 1, f);
    pb = min(max(pb, 0), GG - 1);
    for (int q = pb + 1; q <= b; ++q) gstart[q] = i;
  }
  if (i == NN - 1){ for (int q = b + 1; q <= GG; ++q) gstart[q] = NN; }
}

// ---------------- initial projection: x[N,128] @ Wp[128,64] -> h fp32 ----------------
__global__ __launch_bounds__(256) void k_proj(const void* __restrict__ xraw, const float* __restrict__ Wp32,
                                              float* __restrict__ h, const int* __restrict__ flags){
  __shared__ float xs[64*128];
  __shared__ float wsm[128*64];
  int t = threadIdx.x;
  int r0 = blockIdx.x * 64;
  int rows = NN - r0; if (rows > 64) rows = 64;
  const float4* gw = (const float4*)Wp32;
  #pragma unroll
  for (int i = 0; i < 8; ++i) ((float4*)wsm)[i*256 + t] = gw[i*256 + t];
  int f32 = flags[2];
  #pragma unroll
  for (int i = 0; i < 8; ++i){
    int p = i*256 + t;
    int r = p >> 5, kq = p & 31;
    float4 v = make_float4(0.f,0.f,0.f,0.f);
    if (r < rows){
      if (f32) v = ((const float4*)xraw)[(size_t)(r0 + r)*32 + kq];
      else {
        uint2 u = ((const uint2*)xraw)[(size_t)(r0 + r)*32 + kq];
        unpack2(u.x, v.x, v.y); unpack2(u.y, v.z, v.w);
      }
    }
    *(float4*)&xs[r*128 + kq*4] = v;
  }
  __syncthreads();
  int tx = t & 15, ty = t >> 4;
  int c0 = tx*4, rr0 = ty*4;
  float acc[4][4] = {{0.f}};
  for (int k = 0; k < 128; k += 4){
    float4 xv[4];
    #pragma unroll
    for (int i = 0; i < 4; ++i) xv[i] = *(const float4*)&xs[(rr0 + i)*128 + k];
    const float* xf = (const float*)xv;
    #pragma unroll
    for (int m = 0; m < 4; ++m){
      float4 wv = *(const float4*)&wsm[(k + m)*64 + c0];
      #pragma unroll
      for (int i = 0; i < 4; ++i){
        float xm = xf[i*4 + m];
        acc[i][0] = fmaf(xm, wv.x, acc[i][0]);
        acc[i][1] = fmaf(xm, wv.y, acc[i][1]);
        acc[i][2] = fmaf(xm, wv.z, acc[i][2]);
        acc[i][3] = fmaf(xm, wv.w, acc[i][3]);
      }
    }
  }
  #pragma unroll
  for (int i = 0; i < 4; ++i){
    int r = rr0 + i;
    if (r < rows){
      float4 o;
      o.x = clamp4(acc[i][0]); o.y = clamp4(acc[i][1]);
      o.z = clamp4(acc[i][2]); o.w = clamp4(acc[i][3]);
      *(float4*)&h[(size_t)(r0 + r)*64 + c0] = o;
    }
  }
}

// ---------------- per-layer dual GEMM as [N,64]@[64,512], fused norm+SELU on input ----------------
__global__ __launch_bounds__(256) void k_gemm2t(const float* __restrict__ h,
    const float* __restrict__ Wl, const float* __restrict__ bl,
    const float* __restrict__ Wr, const float* __restrict__ br,
    bf16* __restrict__ xl, bf16* __restrict__ xr,
    const float* __restrict__ stats, const float* __restrict__ lnw, const float* __restrict__ lnb,
    int apply){
  __shared__ float hs[64*68];        // padded row: 68
  __shared__ float ws2[64*128];
  int t = threadIdx.x;
  int r0 = blockIdx.x * 64;
  int ct = blockIdx.y;               // 0..3
  int rows = NN - r0; if (rows > 64) rows = 64;
  const float* Wsrc = (ct < 2) ? Wl : Wr;
  const float* bsrc = (ct < 2) ? bl : br;
  bf16* out = (ct < 2) ? xl : xr;
  int cb = (ct & 1) * 128;
  float mu = 0.f, inv = 0.f;
  if (apply){ mu = stats[0]; inv = stats[1]; }
  // stage h tile (fused norm+SELU when apply)
  #pragma unroll
  for (int i = 0; i < 4; ++i){
    int p = i*256 + t;
    int r = p >> 4, kq = p & 15;
    float4 v = make_float4(0.f,0.f,0.f,0.f);
    if (r < rows){
      v = ((const float4*)h)[(size_t)(r0 + r)*16 + kq];
      if (apply){
        float4 w4 = *(const float4*)(lnw + kq*4);
        float4 b4 = *(const float4*)(lnb + kq*4);
        v.x = selu_f((v.x - mu)*inv*w4.x + b4.x);
        v.y = selu_f((v.y - mu)*inv*w4.y + b4.y);
        v.z = selu_f((v.z - mu)*inv*w4.z + b4.z);
        v.w = selu_f((v.w - mu)*inv*w4.w + b4.w);
      }
    }
    *(float4*)&hs[r*68 + kq*4] = v;
  }
  #pragma unroll
  for (int i = 0; i < 8; ++i){
    int p = i*256 + t;
    int k = p >> 5, cq = p & 31;
    ((float4*)ws2)[k*32 + cq] = ((const float4*)Wsrc)[k*64 + (cb >> 2) + cq];
  }
  __syncthreads();
  int tx = t & 15, ty = t >> 4;
  int c0 = tx*4, rr0 = ty*4;
  float acc[4][8] = {{0.f}};
  for (int k = 0; k < 64; k += 4){
    float4 xv[4];
    #pragma unroll
    for (int i = 0; i < 4; ++i) xv[i] = *(const float4*)&hs[(rr0 + i)*68 + k];
    const float* xf = (const float*)xv;
    #pragma unroll
    for (int m = 0; m < 4; ++m){
      float4 w0 = *(const float4*)&ws2[(k + m)*128 + c0];
      float4 w1 = *(const float4*)&ws2[(k + m)*128 + 64 + c0];
      #pragma unroll
      for (int i = 0; i < 4; ++i){
        float xm = xf[i*4 + m];
        acc[i][0] = fmaf(xm, w0.x, acc[i][0]);
        acc[i][1] = fmaf(xm, w0.y, acc[i][1]);
        acc[i][2] = fmaf(xm, w0.z, acc[i][2]);
        acc[i][3] = fmaf(xm, w0.w, acc[i][3]);
        acc[i][4] = fmaf(xm, w1.x, acc[i][4]);
        acc[i][5] = fmaf(xm, w1.y, acc[i][5]);
        acc[i][6] = fmaf(xm, w1.z, acc[i][6]);
        acc[i][7] = fmaf(xm, w1.w, acc[i][7]);
      }
    }
  }
  float4 bb0 = *(const float4*)&bsrc[cb + c0];
  float4 bb1 = *(const float4*)&bsrc[cb + 64 + c0];
  #pragma unroll
  for (int i = 0; i < 4; ++i){
    int r = rr0 + i;
    if (r < rows){
      size_t base = (size_t)(r0 + r)*256;
      uint2 p0, p1;
      p0.x = pack2bf(acc[i][0] + bb0.x, acc[i][1] + bb0.y);
      p0.y = pack2bf(acc[i][2] + bb0.z, acc[i][3] + bb0.w);
      p1.x = pack2bf(acc[i][4] + bb1.x, acc[i][5] + bb1.y);
      p1.y = pack2bf(acc[i][6] + bb1.z, acc[i][7] + bb1.w);
      *(uint2*)&out[base + cb + c0]      = p0;
      *(uint2*)&out[base + cb + 64 + c0] = p1;
    }
  }
}

// ---------------- GATv2: one wave per dst node (R6-proven memory pattern) ----------------
// lane holds 4 contiguous channels (8 B) of the 512 B row; head = lane>>4; ssrc load is wave-uniform (scalar)
// fused: GraphNorm stats into 256-bucket arrays (buckets[0..255]=sum, [256..511]=sumsq)
__global__ __launch_bounds__(64) void k_gat(const bf16* __restrict__ xl, const bf16* __restrict__ xr,
    const int* __restrict__ off, const int* __restrict__ ssrc,
    const float* __restrict__ att, const float* __restrict__ cbp,
    float* __restrict__ out, float* __restrict__ buckets){
  int d = blockIdx.x;
  int lane = threadIdx.x;
  int s0 = off[d], s1 = off[d + 1];
  int head = lane >> 4;
  int c4 = (lane & 15) * 4;

  float4 av = *(const float4*)(att + head*64 + c4);
  uint2 ur = *(const uint2*)(xr + (size_t)d * 256 + lane*4);
  float r0, r1, r2, r3; unpack2(ur.x, r0, r1); unpack2(ur.y, r2, r3);
  const float NS = 0.2f;

  float denom = 0.f, m0 = 0.f, m1 = 0.f, m2 = 0.f, m3 = 0.f;
  for (int e = s0; e < s1; ++e){
    int ofs = ssrc[e];                                   // wave-uniform -> scalar load
    uint2 u = *(const uint2*)((const char*)xl + (size_t)(unsigned)ofs + lane*8);
    float x0, x1, x2, x3; unpack2(u.x, x0, x1); unpack2(u.y, x2, x3);
    float t0 = x0 + r0, t1 = x1 + r1, t2 = x2 + r2, t3 = x3 + r3;
    t0 = fmaxf(t0, NS*t0); t1 = fmaxf(t1, NS*t1); t2 = fmaxf(t2, NS*t2); t3 = fmaxf(t3, NS*t3);
    float sc = av.x*t0; sc = fmaf(av.y, t1, sc); sc = fmaf(av.z, t2, sc); sc = fmaf(av.w, t3, sc);
    sc += __shfl_xor(sc, 1, 64); sc += __shfl_xor(sc, 2, 64);
    sc += __shfl_xor(sc, 4, 64); sc += __shfl_xor(sc, 8, 64);
    sc = fminf(sc, 30.f);
    float p = __expf(sc);
    denom += p;
    m0 = fmaf(p, x0, m0); m1 = fmaf(p, x1, m1); m2 = fmaf(p, x2, m2); m3 = fmaf(p, x3, m3);
  }
  float inv = denom > 0.f ? 1.0f / denom : 0.f;
  float v0 = m0*inv, v1 = m1*inv, v2 = m2*inv, v3 = m3*inv;
  // head mean across the 4 head groups
  v0 += __shfl_xor(v0, 16, 64); v1 += __shfl_xor(v1, 16, 64);
  v2 += __shfl_xor(v2, 16, 64); v3 += __shfl_xor(v3, 16, 64);
  v0 += __shfl_xor(v0, 32, 64); v1 += __shfl_xor(v1, 32, 64);
  v2 += __shfl_xor(v2, 32, 64); v3 += __shfl_xor(v3, 32, 64);
  if (lane < 16){
    float4 cbv = *(const float4*)(cbp + c4);
    float4 o;
    o.x = clamp4(0.25f*v0 + cbv.x); o.y = clamp4(0.25f*v1 + cbv.y);
    o.z = clamp4(0.25f*v2 + cbv.z); o.w = clamp4(0.25f*v3 + cbv.w);
    ((float4*)(out + (size_t)d * 64))[lane] = o;
    // fused GraphNorm stats (16 lanes x 4 ch)
    float s1p = o.x + o.y + o.z + o.w;
    float s2p = o.x*o.x + o.y*o.y + o.z*o.z + o.w*o.w;
    s1p += __shfl_xor(s1p, 1, 64); s2p += __shfl_xor(s2p, 1, 64);
    s1p += __shfl_xor(s1p, 2, 64); s2p += __shfl_xor(s2p, 2, 64);
    s1p += __shfl_xor(s1p, 4, 64); s2p += __shfl_xor(s2p, 4, 64);
    s1p += __shfl_xor(s1p, 8, 64); s2p += __shfl_xor(s2p, 8, 64);
    if (lane == 0){
      atomicAdd(&buckets[d & 255], s1p);
      atomicAdd(&buckets[256 + (d & 255)], s2p);
    }
  }
}

// ---------------- GraphNorm finalize: reduce buckets -> stats, re-zero buckets ----------------
__global__ __launch_bounds__(256) void k_normfin(float* __restrict__ partials, float* __restrict__ stats){
  int t = threadIdx.x;
  float s1 = partials[t], s2 = partials[256 + t];
  partials[t] = 0.f; partials[256 + t] = 0.f;
  #pragma unroll
  for (int dl = 1; dl < 64; dl <<= 1){ s1 += __shfl_xor(s1, dl, 64); s2 += __shfl_xor(s2, dl, 64); }
  __shared__ float l1[4], l2[4];
  int w = t >> 6;
  if ((t & 63) == 0){ l1[w] = s1; l2[w] = s2; }
  __syncthreads();
  if (t == 0){
    float t1 = l1[0] + l1[1] + l1[2] + l1[3];
    float t2 = l2[0] + l2[1] + l2[2] + l2[3];
    float cnt = (float)(NN * 64);
    float mu = t1 / cnt;
    float var = t2 / cnt - mu*mu;
    if (!(var > 0.f)) var = 0.f;
    stats[0] = mu;
    stats[1] = 1.0f / (sqrtf(var) + 1e-5f);
  }
}

// ---------------- pool stage A: fused norm+SELU, partial sums into pooled[G][64] ----------------
__global__ __launch_bounds__(256) void k_poolA(const float* __restrict__ h, const void* __restrict__ batch,
                                               float* __restrict__ pooled, const int* __restrict__ flags,
                                               const float* __restrict__ stats,
                                               const float* __restrict__ lnw, const float* __restrict__ lnb){
  int t = threadIdx.x;
  int c = t & 63, rq = t >> 6;
  int r0 = blockIdx.x * 256;
  int r1 = r0 + 256; if (r1 > NN) r1 = NN;
  int f = flags[1];
  float mu = stats[0], inv = stats[1];
  float wc = lnw[c], bc = lnb[c];
  float acc = 0.f;
  int cur_g = -1;
  for (int r = r0 + rq; r < r1; r += 4){
    int g = ld_i(batch, r, f);
    g = min(max(g, 0), GG - 1);
    if (g != cur_g){
      if (cur_g >= 0) atomicAdd(&pooled[cur_g*64 + c], acc);
      acc = 0.f; cur_g = g;
    }
    acc += selu_f((h[(size_t)r*64 + c] - mu)*inv*wc + bc);
  }
  if (cur_g >= 0) atomicAdd(&pooled[cur_g*64 + c], acc);
}

// ---------------- pool stage B: finalize (mean, dot Wh, +bh) ----------------
__global__ __launch_bounds__(64) void k_poolB(const float* __restrict__ pooled, const int* __restrict__ gstart,
    const float* __restrict__ Wh, const float* __restrict__ bh, void* __restrict__ outp,
    const int* __restrict__ flags){
  int g = blockIdx.x, t = threadIdx.x;   // 64 threads
  int rs = gstart[g], re = gstart[g + 1];
  int cnt = re - rs; if (cnt < 1) cnt = 1;
  float val = (pooled[g*64 + t] / (float)cnt) * Wh[t];
  #pragma unroll
  for (int dl = 1; dl < 64; dl <<= 1) val += __shfl_xor(val, dl, 64);
  if (t == 0){
    float res = val + bh[0];
    if (flags[2]) ((float*)outp)[g] = res;
    else          ((bf16*)outp)[g] = f2b(res);
  }
}

extern "C" void kernel_launch(void* const* d_in, const int* in_sizes, int n_in,
                              void* d_out, int out_size, void* d_ws, size_t ws_size,
                              hipStream_t stream) {
  const void* x     = d_in[0];
  const void* ei    = d_in[1];
  const void* batch = d_in[2];
  const void* Wp    = d_in[3];
  const void* Wl    = d_in[4];
  const void* bl    = d_in[5];
  const void* Wr    = d_in[6];
  const void* br    = d_in[7];
  const void* att   = d_in[8];
  const void* cb    = d_in[9];
  const void* lnw   = d_in[10];
  const void* lnb   = d_in[11];
  const void* Wh    = d_in[12];
  const void* bh    = d_in[13];

  char* w = (char*)d_ws;
  int*   flags  = (int*)w;     w += 256;
  int*   deg    = (int*)w;     w += 200192;
  int*   off    = (int*)w;     w += 200192;
  int*   cursor = (int*)w;     w += 200192;
  int*   btot   = (int*)w;     w += 1024;
  int*   boff   = (int*)w;     w += 1024;
  int*   gstart = (int*)w;     w += 256;
  float* partials = (float*)w; w += 2048;            // 512 floats (stat buckets)
  float* pooled = (float*)w;   w += GG*64*4;         // adjacent to partials: zeroed together
  float* stats  = (float*)w;   w += 256;
  float* wcvt   = (float*)w;   w += 572928;          // 143169 fp32 canonical weights
  int*   ssrc   = (int*)w;     w += (size_t)EE*4;
  float* hbuf   = (float*)w;   w += (size_t)NN*64*4;
  bf16*  xlb    = (bf16*)w;    w += (size_t)NN*256*2;
  bf16*  xrb    = (bf16*)w;    w += (size_t)NN*256*2;

  float* Wp32  = wcvt;
  float* Wl32  = wcvt + 8192;
  float* bl32  = wcvt + 73728;
  float* Wr32  = wcvt + 74752;
  float* br32  = wcvt + 140288;
  float* att32 = wcvt + 141312;
  float* cb32  = wcvt + 142336;
  float* lnw32 = wcvt + 142592;
  float* lnb32 = wcvt + 142848;
  float* Wh32  = wcvt + 143104;
  float* bh32  = wcvt + 143168;

  const int NB = (NN + 255) / 256;   // 196
  const int NT = (NN + 63) / 64;     // 782

  k_detect<<<1, 64, 0, stream>>>(ei, batch, lnw, flags);
  k_zero<<<NB, 256, 0, stream>>>(deg, NN);
  k_zero<<<(512 + GG*64 + 255)/256, 256, 0, stream>>>((int*)partials, 512 + GG*64);
  k_cvt<<<(143169 + 255)/256, 256, 0, stream>>>(Wp, Wl, bl, Wr, br, att, cb, lnw, lnb, Wh, bh, wcvt, flags);
  k_hist<<<(EE + 255)/256, 256, 0, stream>>>(ei, deg, flags);
  k_scan1<<<NB, 256, 0, stream>>>(deg, off, btot);
  k_scan2<<<1, 256, 0, stream>>>(btot, boff, NB);
  k_scan3<<<NB, 256, 0, stream>>>(off, cursor, deg, boff);
  k_scatter<<<(EE + 255)/256, 256, 0, stream>>>(ei, cursor, ssrc, flags);
  k_gbounds<<<NB, 256, 0, stream>>>(batch, gstart, flags);

  k_proj<<<NT, 256, 0, stream>>>(x, Wp32, hbuf, flags);

  for (int l = 0; l < LL; ++l){
    int lp = (l > 0) ? (l - 1) : 0;
    k_gemm2t<<<dim3(NT, 4), 256, 0, stream>>>(hbuf,
        Wl32 + (size_t)l*64*256, bl32 + (size_t)l*256,
        Wr32 + (size_t)l*64*256, br32 + (size_t)l*256, xlb, xrb,
        stats, lnw32 + (size_t)lp*CC, lnb32 + (size_t)lp*CC, l > 0 ? 1 : 0);
    k_gat<<<NN, 64, 0, stream>>>(xlb, xrb, off, ssrc,
        att32 + (size_t)l*HH*CC, cb32 + (size_t)l*CC, hbuf, partials);
    k_normfin<<<1, 256, 0, stream>>>(partials, stats);
  }

  k_poolA<<<NB, 256, 0, stream>>>(hbuf, batch, pooled, flags, stats,
      lnw32 + (size_t)3*CC, lnb32 + (size_t)3*CC);
  k_poolB<<<GG, 64, 0, stream>>>(pooled, gstart, Wh32, bh32, d_out, flags);
}

// Round 9
// 636.257 us; speedup vs baseline: 1.1996x; 1.1996x over previous
//
#include <hip/hip_runtime.h>
#include <hip/hip_bf16.h>
#include <math.h>

#define NN 50000
#define FIN 128
#define CC 64
#define HH 4
#define HC 256
#define EE 500000
#define GG 32
#define LL 4

typedef __hip_bfloat16 bf16;

__device__ __forceinline__ float b2f(bf16 v){ return __bfloat162float(v); }
__device__ __forceinline__ bf16 f2b(float v){ return __float2bfloat16(v); }
__device__ __forceinline__ void unpack2(unsigned u, float& a, float& b){
  union { unsigned q; float f; } x, y;
  x.q = u << 16; y.q = u & 0xffff0000u; a = x.f; b = y.f;
}
__device__ __forceinline__ float clamp4(float v){ return fminf(fmaxf(v, -1e4f), 1e4f); }
__device__ __forceinline__ unsigned pack2bf(float a, float b){
  bf16 x = f2b(clamp4(a)), y = f2b(clamp4(b));
  unsigned short ux = *(unsigned short*)&x, uy = *(unsigned short*)&y;
  return (unsigned)ux | ((unsigned)uy << 16);
}
__device__ __forceinline__ float selu_f(float y){
  const float SS = 1.0507009873554805f, SA = 1.6732632423543772f;
  return y > 0.f ? SS*y : SS*SA*(__expf(y) - 1.f);
}
// flag-aware integer load: w8!=0 -> int64, else int32
__device__ __forceinline__ int ld_i(const void* p, int i, int w8){
  if (w8) return (int)((const long long*)p)[i];
  return ((const int*)p)[i];
}

// flags[0]: edge_index is int64; flags[1]: batch is int64; flags[2]: floats are fp32
__global__ void k_detect(const void* ei, const void* batch, const void* lnw, int* flags){
  int lane = threadIdx.x;           // 64 threads
  const int* w  = (const int*)ei;
  const int* wb = (const int*)batch;
  int bad_e = (lane < 32) ? (w[2*(lane*15625) + 1] != 0) : 0;
  int bad_b = (lane < 32) ? (wb[25001 + 2*lane] != 0) : 0;
  unsigned long long me = __ballot(bad_e);
  unsigned long long mb = __ballot(bad_b);
  if (lane == 0){
    flags[0] = (me == 0ULL) ? 1 : 0;
    flags[1] = (mb == 0ULL) ? 1 : 0;
    const unsigned short* lw = (const unsigned short*)lnw;
    flags[2] = (lw[0] == 0x0000 && lw[1] == 0x3F80) ? 1 : 0;
  }
}

__global__ __launch_bounds__(256) void k_zero(int* p, int n){
  int i = blockIdx.x*256 + threadIdx.x;
  if (i < n) p[i] = 0;
}

// ---- convert all small weights to canonical fp32 (143169 elements total) ----
__global__ __launch_bounds__(256) void k_cvt(
    const void* Wp, const void* Wl, const void* bl, const void* Wr, const void* br,
    const void* att, const void* cb, const void* lnw, const void* lnb,
    const void* Wh, const void* bh, float* dst, const int* flags){
  int i = blockIdx.x*256 + threadIdx.x;
  if (i >= 143169) return;
  const void* src; int idx;
  if      (i < 8192)   { src = Wp;  idx = i; }
  else if (i < 73728)  { src = Wl;  idx = i - 8192; }
  else if (i < 74752)  { src = bl;  idx = i - 73728; }
  else if (i < 140288) { src = Wr;  idx = i - 74752; }
  else if (i < 141312) { src = br;  idx = i - 140288; }
  else if (i < 142336) { src = att; idx = i - 141312; }
  else if (i < 142592) { src = cb;  idx = i - 142336; }
  else if (i < 142848) { src = lnw; idx = i - 142592; }
  else if (i < 143104) { src = lnb; idx = i - 142848; }
  else if (i < 143168) { src = Wh;  idx = i - 143104; }
  else                 { src = bh;  idx = 0; }
  float v = flags[2] ? ((const float*)src)[idx] : b2f(((const bf16*)src)[idx]);
  dst[i] = v;
}

// ---------------- edge histogram by dst ----------------
__global__ __launch_bounds__(256) void k_hist(const void* __restrict__ ei, int* __restrict__ deg,
                                              const int* __restrict__ flags){
  int e = blockIdx.x*256 + threadIdx.x;
  if (e < EE){
    int d = ld_i(ei, EE + e, flags[0]);
    if ((unsigned)d < NN) atomicAdd(&deg[d], 1);
  }
}

// ---------------- parallel 3-stage exclusive scan over deg[NN] ----------------
__global__ __launch_bounds__(256) void k_scan1(const int* __restrict__ deg, int* __restrict__ off,
                                               int* __restrict__ btot){
  int t = threadIdx.x;
  int i = blockIdx.x*256 + t;
  int v = (i < NN) ? deg[i] : 0;
  int incl = v;
  #pragma unroll
  for (int dl = 1; dl < 64; dl <<= 1){
    int u = __shfl_up(incl, dl, 64);
    if ((t & 63) >= dl) incl += u;
  }
  __shared__ int wt[4];
  if ((t & 63) == 63) wt[t >> 6] = incl;
  __syncthreads();
  int base = 0;
  for (int ww = 0; ww < (t >> 6); ++ww) base += wt[ww];
  incl += base;
  if (i < NN) off[i + 1] = incl;
  if (t == 255) btot[blockIdx.x] = incl;
}

__global__ __launch_bounds__(256) void k_scan2(const int* __restrict__ btot, int* __restrict__ boff, int nb){
  int t = threadIdx.x;
  int v = (t < nb) ? btot[t] : 0;
  int incl = v;
  #pragma unroll
  for (int dl = 1; dl < 64; dl <<= 1){
    int u = __shfl_up(incl, dl, 64);
    if ((t & 63) >= dl) incl += u;
  }
  __shared__ int wt[4];
  if ((t & 63) == 63) wt[t >> 6] = incl;
  __syncthreads();
  int base = 0;
  for (int ww = 0; ww < (t >> 6); ++ww) base += wt[ww];
  incl += base;
  if (t < 256) boff[t] = incl - v;   // exclusive
}

__global__ __launch_bounds__(256) void k_scan3(int* __restrict__ off, int* __restrict__ cursor,
                                               const int* __restrict__ deg, const int* __restrict__ boff){
  int i = blockIdx.x*256 + threadIdx.x;
  if (i >= NN) return;
  int v = off[i + 1] + boff[i >> 8];
  off[i + 1] = v;
  cursor[i] = v - deg[i];
  if (i == 0) off[0] = 0;
}

// ssrc stores BYTE offsets of the src row (s * 512)
__global__ __launch_bounds__(256) void k_scatter(const void* __restrict__ ei, int* __restrict__ cursor,
                                                 int* __restrict__ ssrc, const int* __restrict__ flags){
  int e = blockIdx.x*256 + threadIdx.x;
  if (e < EE){
    int f = flags[0];
    int s = ld_i(ei, e, f);
    int d = ld_i(ei, EE + e, f);
    if ((unsigned)d < NN && (unsigned)s < NN){
      int p = atomicAdd(&cursor[d], 1);
      ssrc[p] = s << 9;
    }
  }
}

// ---------------- graph boundaries (batch sorted) ----------------
__global__ __launch_bounds__(256) void k_gbounds(const void* __restrict__ batch, int* __restrict__ gstart,
                                                 const int* __restrict__ flags){
  int i = blockIdx.x*256 + threadIdx.x;
  if (i >= NN) return;
  int f = flags[1];
  int b = ld_i(batch, i, f);
  b = min(max(b, 0), GG - 1);
  if (i == 0){ for (int q = 0; q <= b; ++q) gstart[q] = 0; }
  else {
    int pb = ld_i(batch, i - 1, f);
    pb = min(max(pb, 0), GG - 1);
    for (int q = pb + 1; q <= b; ++q) gstart[q] = i;
  }
  if (i == NN - 1){ for (int q = b + 1; q <= GG; ++q) gstart[q] = NN; }
}

// ---------------- initial projection: x[N,128] @ Wp[128,64] -> h fp32 ----------------
__global__ __launch_bounds__(256) void k_proj(const void* __restrict__ xraw, const float* __restrict__ Wp32,
                                              float* __restrict__ h, const int* __restrict__ flags){
  __shared__ float xs[64*128];
  __shared__ float wsm[128*64];
  int t = threadIdx.x;
  int r0 = blockIdx.x * 64;
  int rows = NN - r0; if (rows > 64) rows = 64;
  const float4* gw = (const float4*)Wp32;
  #pragma unroll
  for (int i = 0; i < 8; ++i) ((float4*)wsm)[i*256 + t] = gw[i*256 + t];
  int f32 = flags[2];
  #pragma unroll
  for (int i = 0; i < 8; ++i){
    int p = i*256 + t;
    int r = p >> 5, kq = p & 31;
    float4 v = make_float4(0.f,0.f,0.f,0.f);
    if (r < rows){
      if (f32) v = ((const float4*)xraw)[(size_t)(r0 + r)*32 + kq];
      else {
        uint2 u = ((const uint2*)xraw)[(size_t)(r0 + r)*32 + kq];
        unpack2(u.x, v.x, v.y); unpack2(u.y, v.z, v.w);
      }
    }
    *(float4*)&xs[r*128 + kq*4] = v;
  }
  __syncthreads();
  int tx = t & 15, ty = t >> 4;
  int c0 = tx*4, rr0 = ty*4;
  float acc[4][4] = {{0.f}};
  for (int k = 0; k < 128; k += 4){
    float4 xv[4];
    #pragma unroll
    for (int i = 0; i < 4; ++i) xv[i] = *(const float4*)&xs[(rr0 + i)*128 + k];
    const float* xf = (const float*)xv;
    #pragma unroll
    for (int m = 0; m < 4; ++m){
      float4 wv = *(const float4*)&wsm[(k + m)*64 + c0];
      #pragma unroll
      for (int i = 0; i < 4; ++i){
        float xm = xf[i*4 + m];
        acc[i][0] = fmaf(xm, wv.x, acc[i][0]);
        acc[i][1] = fmaf(xm, wv.y, acc[i][1]);
        acc[i][2] = fmaf(xm, wv.z, acc[i][2]);
        acc[i][3] = fmaf(xm, wv.w, acc[i][3]);
      }
    }
  }
  #pragma unroll
  for (int i = 0; i < 4; ++i){
    int r = rr0 + i;
    if (r < rows){
      float4 o;
      o.x = clamp4(acc[i][0]); o.y = clamp4(acc[i][1]);
      o.z = clamp4(acc[i][2]); o.w = clamp4(acc[i][3]);
      *(float4*)&h[(size_t)(r0 + r)*64 + c0] = o;
    }
  }
}

// ---------------- per-layer dual GEMM as [N,64]@[64,512], fused norm+SELU on input ----------------
__global__ __launch_bounds__(256) void k_gemm2t(const float* __restrict__ h,
    const float* __restrict__ Wl, const float* __restrict__ bl,
    const float* __restrict__ Wr, const float* __restrict__ br,
    bf16* __restrict__ xl, bf16* __restrict__ xr,
    const float* __restrict__ stats, const float* __restrict__ lnw, const float* __restrict__ lnb,
    int apply){
  __shared__ float hs[64*68];        // padded row: 68
  __shared__ float ws2[64*128];
  int t = threadIdx.x;
  int r0 = blockIdx.x * 64;
  int ct = blockIdx.y;               // 0..3
  int rows = NN - r0; if (rows > 64) rows = 64;
  const float* Wsrc = (ct < 2) ? Wl : Wr;
  const float* bsrc = (ct < 2) ? bl : br;
  bf16* out = (ct < 2) ? xl : xr;
  int cb = (ct & 1) * 128;
  float mu = 0.f, inv = 0.f;
  if (apply){ mu = stats[0]; inv = stats[1]; }
  // stage h tile (fused norm+SELU when apply)
  #pragma unroll
  for (int i = 0; i < 4; ++i){
    int p = i*256 + t;
    int r = p >> 4, kq = p & 15;
    float4 v = make_float4(0.f,0.f,0.f,0.f);
    if (r < rows){
      v = ((const float4*)h)[(size_t)(r0 + r)*16 + kq];
      if (apply){
        float4 w4 = *(const float4*)(lnw + kq*4);
        float4 b4 = *(const float4*)(lnb + kq*4);
        v.x = selu_f((v.x - mu)*inv*w4.x + b4.x);
        v.y = selu_f((v.y - mu)*inv*w4.y + b4.y);
        v.z = selu_f((v.z - mu)*inv*w4.z + b4.z);
        v.w = selu_f((v.w - mu)*inv*w4.w + b4.w);
      }
    }
    *(float4*)&hs[r*68 + kq*4] = v;
  }
  #pragma unroll
  for (int i = 0; i < 8; ++i){
    int p = i*256 + t;
    int k = p >> 5, cq = p & 31;
    ((float4*)ws2)[k*32 + cq] = ((const float4*)Wsrc)[k*64 + (cb >> 2) + cq];
  }
  __syncthreads();
  int tx = t & 15, ty = t >> 4;
  int c0 = tx*4, rr0 = ty*4;
  float acc[4][8] = {{0.f}};
  for (int k = 0; k < 64; k += 4){
    float4 xv[4];
    #pragma unroll
    for (int i = 0; i < 4; ++i) xv[i] = *(const float4*)&hs[(rr0 + i)*68 + k];
    const float* xf = (const float*)xv;
    #pragma unroll
    for (int m = 0; m < 4; ++m){
      float4 w0 = *(const float4*)&ws2[(k + m)*128 + c0];
      float4 w1 = *(const float4*)&ws2[(k + m)*128 + 64 + c0];
      #pragma unroll
      for (int i = 0; i < 4; ++i){
        float xm = xf[i*4 + m];
        acc[i][0] = fmaf(xm, w0.x, acc[i][0]);
        acc[i][1] = fmaf(xm, w0.y, acc[i][1]);
        acc[i][2] = fmaf(xm, w0.z, acc[i][2]);
        acc[i][3] = fmaf(xm, w0.w, acc[i][3]);
        acc[i][4] = fmaf(xm, w1.x, acc[i][4]);
        acc[i][5] = fmaf(xm, w1.y, acc[i][5]);
        acc[i][6] = fmaf(xm, w1.z, acc[i][6]);
        acc[i][7] = fmaf(xm, w1.w, acc[i][7]);
      }
    }
  }
  float4 bb0 = *(const float4*)&bsrc[cb + c0];
  float4 bb1 = *(const float4*)&bsrc[cb + 64 + c0];
  #pragma unroll
  for (int i = 0; i < 4; ++i){
    int r = rr0 + i;
    if (r < rows){
      size_t base = (size_t)(r0 + r)*256;
      uint2 p0, p1;
      p0.x = pack2bf(acc[i][0] + bb0.x, acc[i][1] + bb0.y);
      p0.y = pack2bf(acc[i][2] + bb0.z, acc[i][3] + bb0.w);
      p1.x = pack2bf(acc[i][4] + bb1.x, acc[i][5] + bb1.y);
      p1.y = pack2bf(acc[i][6] + bb1.z, acc[i][7] + bb1.w);
      *(uint2*)&out[base + cb + c0]      = p0;
      *(uint2*)&out[base + cb + 64 + c0] = p1;
    }
  }
}

// ---------------- GATv2: one wave per dst node (R6-proven memory pattern) ----------------
// lane holds 4 contiguous channels (8 B) of the 512 B row; ssrc load is wave-uniform (scalar)
// fused stats: lane 0 writes per-node {sum, sumsq} as a plain float2 store (NO atomics)
__global__ __launch_bounds__(64) void k_gat(const bf16* __restrict__ xl, const bf16* __restrict__ xr,
    const int* __restrict__ off, const int* __restrict__ ssrc,
    const float* __restrict__ att, const float* __restrict__ cbp,
    float* __restrict__ out, float2* __restrict__ nstat){
  int d = blockIdx.x;
  int lane = threadIdx.x;
  int s0 = off[d], s1 = off[d + 1];
  int head = lane >> 4;
  int c4 = (lane & 15) * 4;

  float4 av = *(const float4*)(att + head*64 + c4);
  uint2 ur = *(const uint2*)(xr + (size_t)d * 256 + lane*4);
  float r0, r1, r2, r3; unpack2(ur.x, r0, r1); unpack2(ur.y, r2, r3);
  const float NS = 0.2f;

  float denom = 0.f, m0 = 0.f, m1 = 0.f, m2 = 0.f, m3 = 0.f;
  for (int e = s0; e < s1; ++e){
    int ofs = ssrc[e];                                   // wave-uniform -> scalar load
    uint2 u = *(const uint2*)((const char*)xl + (size_t)(unsigned)ofs + lane*8);
    float x0, x1, x2, x3; unpack2(u.x, x0, x1); unpack2(u.y, x2, x3);
    float t0 = x0 + r0, t1 = x1 + r1, t2 = x2 + r2, t3 = x3 + r3;
    t0 = fmaxf(t0, NS*t0); t1 = fmaxf(t1, NS*t1); t2 = fmaxf(t2, NS*t2); t3 = fmaxf(t3, NS*t3);
    float sc = av.x*t0; sc = fmaf(av.y, t1, sc); sc = fmaf(av.z, t2, sc); sc = fmaf(av.w, t3, sc);
    sc += __shfl_xor(sc, 1, 64); sc += __shfl_xor(sc, 2, 64);
    sc += __shfl_xor(sc, 4, 64); sc += __shfl_xor(sc, 8, 64);
    sc = fminf(sc, 30.f);
    float p = __expf(sc);
    denom += p;
    m0 = fmaf(p, x0, m0); m1 = fmaf(p, x1, m1); m2 = fmaf(p, x2, m2); m3 = fmaf(p, x3, m3);
  }
  float inv = denom > 0.f ? 1.0f / denom : 0.f;
  float v0 = m0*inv, v1 = m1*inv, v2 = m2*inv, v3 = m3*inv;
  // head mean across the 4 head groups
  v0 += __shfl_xor(v0, 16, 64); v1 += __shfl_xor(v1, 16, 64);
  v2 += __shfl_xor(v2, 16, 64); v3 += __shfl_xor(v3, 16, 64);
  v0 += __shfl_xor(v0, 32, 64); v1 += __shfl_xor(v1, 32, 64);
  v2 += __shfl_xor(v2, 32, 64); v3 += __shfl_xor(v3, 32, 64);
  if (lane < 16){
    float4 cbv = *(const float4*)(cbp + c4);
    float4 o;
    o.x = clamp4(0.25f*v0 + cbv.x); o.y = clamp4(0.25f*v1 + cbv.y);
    o.z = clamp4(0.25f*v2 + cbv.z); o.w = clamp4(0.25f*v3 + cbv.w);
    ((float4*)(out + (size_t)d * 64))[lane] = o;
    // fused GraphNorm stats (16 lanes x 4 ch) -> plain per-node store
    float s1p = o.x + o.y + o.z + o.w;
    float s2p = o.x*o.x + o.y*o.y + o.z*o.z + o.w*o.w;
    s1p += __shfl_xor(s1p, 1, 64); s2p += __shfl_xor(s2p, 1, 64);
    s1p += __shfl_xor(s1p, 2, 64); s2p += __shfl_xor(s2p, 2, 64);
    s1p += __shfl_xor(s1p, 4, 64); s2p += __shfl_xor(s2p, 4, 64);
    s1p += __shfl_xor(s1p, 8, 64); s2p += __shfl_xor(s2p, 8, 64);
    if (lane == 0){
      float2 ns; ns.x = s1p; ns.y = s2p;
      nstat[d] = ns;
    }
  }
}

// ---------------- nstat reduce: 64 blocks over NN float2 -> partials[0..63],[64..127] ----------------
__global__ __launch_bounds__(256) void k_nstat(const float2* __restrict__ nstat, float* __restrict__ partials){
  int t = threadIdx.x;
  int gid = blockIdx.x*256 + t;
  float s1 = 0.f, s2 = 0.f;
  for (int i = gid; i < NN; i += 64*256){
    float2 v = nstat[i];
    s1 += v.x; s2 += v.y;
  }
  #pragma unroll
  for (int dl = 1; dl < 64; dl <<= 1){ s1 += __shfl_xor(s1, dl, 64); s2 += __shfl_xor(s2, dl, 64); }
  __shared__ float l1[4], l2[4];
  int w = t >> 6;
  if ((t & 63) == 0){ l1[w] = s1; l2[w] = s2; }
  __syncthreads();
  if (t == 0){
    partials[blockIdx.x]      = l1[0] + l1[1] + l1[2] + l1[3];
    partials[64 + blockIdx.x] = l2[0] + l2[1] + l2[2] + l2[3];
  }
}

// ---------------- GraphNorm finalize: reduce 64 partials -> stats ----------------
__global__ void k_normfin(const float* __restrict__ partials, float* __restrict__ stats){
  int t = threadIdx.x;   // 64 threads
  float s1 = partials[t], s2 = partials[64 + t];
  #pragma unroll
  for (int dl = 1; dl < 64; dl <<= 1){ s1 += __shfl_xor(s1, dl, 64); s2 += __shfl_xor(s2, dl, 64); }
  if (t == 0){
    float cnt = (float)(NN * 64);
    float mu = s1 / cnt;
    float var = s2 / cnt - mu*mu;
    if (!(var > 0.f)) var = 0.f;
    stats[0] = mu;
    stats[1] = 1.0f / (sqrtf(var) + 1e-5f);
  }
}

// ---------------- pool stage A: fused norm+SELU, partial sums into pooled[G][64] ----------------
__global__ __launch_bounds__(256) void k_poolA(const float* __restrict__ h, const void* __restrict__ batch,
                                               float* __restrict__ pooled, const int* __restrict__ flags,
                                               const float* __restrict__ stats,
                                               const float* __restrict__ lnw, const float* __restrict__ lnb){
  int t = threadIdx.x;
  int c = t & 63, rq = t >> 6;
  int r0 = blockIdx.x * 256;
  int r1 = r0 + 256; if (r1 > NN) r1 = NN;
  int f = flags[1];
  float mu = stats[0], inv = stats[1];
  float wc = lnw[c], bc = lnb[c];
  float acc = 0.f;
  int cur_g = -1;
  for (int r = r0 + rq; r < r1; r += 4){
    int g = ld_i(batch, r, f);
    g = min(max(g, 0), GG - 1);
    if (g != cur_g){
      if (cur_g >= 0) atomicAdd(&pooled[cur_g*64 + c], acc);
      acc = 0.f; cur_g = g;
    }
    acc += selu_f((h[(size_t)r*64 + c] - mu)*inv*wc + bc);
  }
  if (cur_g >= 0) atomicAdd(&pooled[cur_g*64 + c], acc);
}

// ---------------- pool stage B: finalize (mean, dot Wh, +bh) ----------------
__global__ __launch_bounds__(64) void k_poolB(const float* __restrict__ pooled, const int* __restrict__ gstart,
    const float* __restrict__ Wh, const float* __restrict__ bh, void* __restrict__ outp,
    const int* __restrict__ flags){
  int g = blockIdx.x, t = threadIdx.x;   // 64 threads
  int rs = gstart[g], re = gstart[g + 1];
  int cnt = re - rs; if (cnt < 1) cnt = 1;
  float val = (pooled[g*64 + t] / (float)cnt) * Wh[t];
  #pragma unroll
  for (int dl = 1; dl < 64; dl <<= 1) val += __shfl_xor(val, dl, 64);
  if (t == 0){
    float res = val + bh[0];
    if (flags[2]) ((float*)outp)[g] = res;
    else          ((bf16*)outp)[g] = f2b(res);
  }
}

extern "C" void kernel_launch(void* const* d_in, const int* in_sizes, int n_in,
                              void* d_out, int out_size, void* d_ws, size_t ws_size,
                              hipStream_t stream) {
  const void* x     = d_in[0];
  const void* ei    = d_in[1];
  const void* batch = d_in[2];
  const void* Wp    = d_in[3];
  const void* Wl    = d_in[4];
  const void* bl    = d_in[5];
  const void* Wr    = d_in[6];
  const void* br    = d_in[7];
  const void* att   = d_in[8];
  const void* cb    = d_in[9];
  const void* lnw   = d_in[10];
  const void* lnb   = d_in[11];
  const void* Wh    = d_in[12];
  const void* bh    = d_in[13];

  char* w = (char*)d_ws;
  int*   flags  = (int*)w;     w += 256;
  int*   deg    = (int*)w;     w += 200192;
  int*   off    = (int*)w;     w += 200192;
  int*   cursor = (int*)w;     w += 200192;
  int*   btot   = (int*)w;     w += 1024;
  int*   boff   = (int*)w;     w += 1024;
  int*   gstart = (int*)w;     w += 256;
  float* partials = (float*)w; w += 2048;            // 128 floats used
  float* pooled = (float*)w;   w += GG*64*4;         // adjacent to partials: zeroed together
  float* stats  = (float*)w;   w += 256;
  float* wcvt   = (float*)w;   w += 572928;          // 143169 fp32 canonical weights
  float2* nstat = (float2*)w;  w += (size_t)NN*8;    // per-node {sum, sumsq}
  int*   ssrc   = (int*)w;     w += (size_t)EE*4;
  float* hbuf   = (float*)w;   w += (size_t)NN*64*4;
  bf16*  xlb    = (bf16*)w;    w += (size_t)NN*256*2;
  bf16*  xrb    = (bf16*)w;    w += (size_t)NN*256*2;

  float* Wp32  = wcvt;
  float* Wl32  = wcvt + 8192;
  float* bl32  = wcvt + 73728;
  float* Wr32  = wcvt + 74752;
  float* br32  = wcvt + 140288;
  float* att32 = wcvt + 141312;
  float* cb32  = wcvt + 142336;
  float* lnw32 = wcvt + 142592;
  float* lnb32 = wcvt + 142848;
  float* Wh32  = wcvt + 143104;
  float* bh32  = wcvt + 143168;

  const int NB = (NN + 255) / 256;   // 196
  const int NT = (NN + 63) / 64;     // 782

  k_detect<<<1, 64, 0, stream>>>(ei, batch, lnw, flags);
  k_zero<<<NB, 256, 0, stream>>>(deg, NN);
  k_zero<<<(GG*64 + 255)/256, 256, 0, stream>>>((int*)pooled, GG*64);
  k_cvt<<<(143169 + 255)/256, 256, 0, stream>>>(Wp, Wl, bl, Wr, br, att, cb, lnw, lnb, Wh, bh, wcvt, flags);
  k_hist<<<(EE + 255)/256, 256, 0, stream>>>(ei, deg, flags);
  k_scan1<<<NB, 256, 0, stream>>>(deg, off, btot);
  k_scan2<<<1, 256, 0, stream>>>(btot, boff, NB);
  k_scan3<<<NB, 256, 0, stream>>>(off, cursor, deg, boff);
  k_scatter<<<(EE + 255)/256, 256, 0, stream>>>(ei, cursor, ssrc, flags);
  k_gbounds<<<NB, 256, 0, stream>>>(batch, gstart, flags);

  k_proj<<<NT, 256, 0, stream>>>(x, Wp32, hbuf, flags);

  for (int l = 0; l < LL; ++l){
    int lp = (l > 0) ? (l - 1) : 0;
    k_gemm2t<<<dim3(NT, 4), 256, 0, stream>>>(hbuf,
        Wl32 + (size_t)l*64*256, bl32 + (size_t)l*256,
        Wr32 + (size_t)l*64*256, br32 + (size_t)l*256, xlb, xrb,
        stats, lnw32 + (size_t)lp*CC, lnb32 + (size_t)lp*CC, l > 0 ? 1 : 0);
    k_gat<<<NN, 64, 0, stream>>>(xlb, xrb, off, ssrc,
        att32 + (size_t)l*HH*CC, cb32 + (size_t)l*CC, hbuf, nstat);
    k_nstat<<<64, 256, 0, stream>>>(nstat, partials);
    k_normfin<<<1, 64, 0, stream>>>(partials, stats);
  }

  k_poolA<<<NB, 256, 0, stream>>>(hbuf, batch, pooled, flags, stats,
      lnw32 + (size_t)3*CC, lnb32 + (size_t)3*CC);
  k_poolB<<<GG, 64, 0, stream>>>(pooled, gstart, Wh32, bh32, d_out, flags);
}